// Round 3
// baseline (4186.701 us; speedup 1.0000x reference)
//
#include <hip/hip_runtime.h>

// ---------- constants ----------
#define B_   64
#define P_   196
#define ENC_ 512
#define ATT_ 256
#define DEC_ 256
#define EMB_ 256
#define V_   10000
#define T_   44
#define G4_  1024          // 4*DEC
#define XW_  768           // EMB+ENC (W_ih inner dim)
#define NBLK 256
#define XPAR 98304         // shorts per X parity buffer (Xh 49152 + Xl 49152)

using short8 = __attribute__((ext_vector_type(8))) short;
using f32x4  = __attribute__((ext_vector_type(4))) float;

__device__ __forceinline__ unsigned short f2bf(float f) {
    unsigned int u = __float_as_uint(f);
    unsigned int r = (u + 0x7fffu + ((u >> 16) & 1u)) >> 16;
    return (unsigned short)r;
}
__device__ __forceinline__ float bf2f(unsigned short h) {
    return __uint_as_float(((unsigned int)h) << 16);
}

// ---------- generic 32x32 transpose: dst[k*N + n] = src[n*stride + off + k] ----------
__global__ void k_transpose(const float* __restrict__ src, float* __restrict__ dst,
                            int N, int stride, int off) {
    __shared__ float t[32][33];
    int k0 = blockIdx.x * 32, n0 = blockIdx.y * 32;
    int tx = threadIdx.x & 31, ty = threadIdx.x >> 5;
    for (int r = ty; r < 32; r += 8)
        t[r][tx] = src[(size_t)(n0 + r) * stride + off + k0 + tx];
    __syncthreads();
    for (int r = ty; r < 32; r += 8)
        dst[(size_t)(k0 + r) * N + n0 + tx] = t[tx][r];
}

// ---------- fp32 -> bf16 convert ----------
__global__ void k_cvt(const float* __restrict__ src, unsigned short* __restrict__ dst, int n) {
    int i = blockIdx.x * 256 + threadIdx.x;
    if (i < n) dst[i] = f2bf(src[i]);
}

// ---------- build permuted hi/lo gate weights: rows j' = d*4+gate, cols k (ctx 0..511, h 512..767)
__global__ __launch_bounds__(256) void k_prepW(
        const float* __restrict__ W_ih, const float* __restrict__ W_hh,
        unsigned short* __restrict__ Wgh, unsigned short* __restrict__ Wgl) {
    int jp = blockIdx.x;             // j' in [0,1024)
    int d = jp >> 2, gate = jp & 3;
    int j = gate * 256 + d;          // original row
    for (int kk = 0; kk < 3; kk++) {
        int k = threadIdx.x + 256 * kk;
        float w = (k < ENC_) ? W_ih[(size_t)j * XW_ + k]            // ctx part: cols 0..511
                             : W_hh[(size_t)j * DEC_ + (k - ENC_)]; // h part
        unsigned short hi = f2bf(w);
        Wgh[(size_t)jp * XW_ + k] = hi;
        Wgl[(size_t)jp * XW_ + k] = f2bf(w - bf2f(hi));
    }
}

// ---------- h0/c0 from mean-pooled encoder ----------
__global__ __launch_bounds__(256) void k_init_state(
        const float* __restrict__ enc,
        const float* __restrict__ W_init_h, const float* __restrict__ b_init_h,
        const float* __restrict__ W_init_c, const float* __restrict__ b_init_c,
        float* __restrict__ h0, float* __restrict__ c0) {
    int b = blockIdx.x, tid = threadIdx.x;
    __shared__ float avg[ENC_];
    for (int e = tid; e < ENC_; e += 256) {
        float s = 0.f;
        const float* p = enc + (size_t)b * P_ * ENC_ + e;
        for (int i = 0; i < P_; i++) s += p[(size_t)i * ENC_];
        avg[e] = s * (1.0f / (float)P_);
    }
    __syncthreads();
    int d = tid;
    float hs = b_init_h[d], cs = b_init_c[d];
    const float* wh = W_init_h + (size_t)d * ENC_;
    const float* wc = W_init_c + (size_t)d * ENC_;
    for (int e = 0; e < ENC_; e++) { float a = avg[e]; hs += a * wh[e]; cs += a * wc[e]; }
    h0[b * DEC_ + d] = hs;
    c0[b * DEC_ + d] = cs;
}

// ---------- att1T[b][a][p] fp32 ----------
__global__ __launch_bounds__(256) void k_att1(
        const float* __restrict__ enc, const float* __restrict__ Wea,
        float* __restrict__ att1T) {
    int b = blockIdx.x >> 2, a0 = (blockIdx.x & 3) * 64;
    __shared__ float encT[32][257];
    __shared__ float Wt[64][32];
    int tid = threadIdx.x;
    int pl = tid & 63, ia = tid >> 6;
    float acc[16][4];
#pragma unroll
    for (int k = 0; k < 16; k++)
#pragma unroll
        for (int q = 0; q < 4; q++) acc[k][q] = 0.f;

    for (int e0 = 0; e0 < ENC_; e0 += 32) {
        {
            int j = tid & 31, pr = tid >> 5;
            for (int pass = 0; pass < 32; pass++) {
                int p = pr + pass * 8;
                float v = 0.f;
                if (p < P_) v = enc[((size_t)b * P_ + p) * ENC_ + e0 + j];
                encT[j][p] = v;
            }
            int r = tid >> 2, c0 = (tid & 3) * 8;
#pragma unroll
            for (int i = 0; i < 8; i++)
                Wt[r][c0 + i] = Wea[(size_t)(a0 + r) * ENC_ + e0 + c0 + i];
        }
        __syncthreads();
        for (int e = 0; e < 32; e++) {
            float e0v = encT[e][pl], e1v = encT[e][pl + 64];
            float e2v = encT[e][pl + 128], e3v = encT[e][pl + 192];
#pragma unroll
            for (int k = 0; k < 16; k++) {
                float w = Wt[ia * 16 + k][e];
                acc[k][0] += w * e0v; acc[k][1] += w * e1v;
                acc[k][2] += w * e2v; acc[k][3] += w * e3v;
            }
        }
        __syncthreads();
    }
#pragma unroll
    for (int k = 0; k < 16; k++)
#pragma unroll
        for (int q = 0; q < 4; q++) {
            int p = pl + 64 * q;
            if (p < P_)
                att1T[(size_t)b * (ATT_ * P_) + (size_t)(a0 + ia * 16 + k) * P_ + p] = acc[k][q];
        }
}

// ---------- embW[(t*64+b)][j'] with j' = d*4+gate (permuted), includes biases ----------
__global__ __launch_bounds__(256) void k_embW(
        const int* __restrict__ caption, const float* __restrict__ embedding,
        const float* __restrict__ WiheT, const float* __restrict__ b_ih,
        const float* __restrict__ b_hh, float* __restrict__ embW) {
    int r0 = blockIdx.x * 16, tid = threadIdx.x;
    __shared__ float embL[16][256];
    __shared__ int capL[16];
    if (tid < 16) {
        int r = r0 + tid, t = r >> 6, b = r & 63;
        capL[tid] = caption[b * T_ + t];
    }
    __syncthreads();
#pragma unroll
    for (int lr = 0; lr < 16; lr++)
        embL[lr][tid] = embedding[(size_t)capL[lr] * EMB_ + tid];
    __syncthreads();
    float base0 = b_ih[tid] + b_hh[tid];
    float base1 = b_ih[tid + 256] + b_hh[tid + 256];
    float base2 = b_ih[tid + 512] + b_hh[tid + 512];
    float base3 = b_ih[tid + 768] + b_hh[tid + 768];
    float acc[16][4];
#pragma unroll
    for (int lr = 0; lr < 16; lr++) {
        acc[lr][0] = base0; acc[lr][1] = base1; acc[lr][2] = base2; acc[lr][3] = base3;
    }
    for (int e = 0; e < EMB_; e++) {
        const float* wr = WiheT + (size_t)e * G4_ + tid;
        float w0 = wr[0], w1 = wr[256], w2 = wr[512], w3 = wr[768];
#pragma unroll
        for (int lr = 0; lr < 16; lr++) {
            float ev = embL[lr][e];
            acc[lr][0] += w0 * ev; acc[lr][1] += w1 * ev;
            acc[lr][2] += w2 * ev; acc[lr][3] += w3 * ev;
        }
    }
#pragma unroll
    for (int lr = 0; lr < 16; lr++) {
        // j' = d*4 + gate = tid*4 + q  -> contiguous float4
        float4 st = make_float4(acc[lr][0], acc[lr][1], acc[lr][2], acc[lr][3]);
        *reinterpret_cast<float4*>(&embW[(size_t)(r0 + lr) * G4_ + tid * 4]) = st;
    }
}

// ---------- persistent cooperative recurrence ----------
// grid = 256 blocks x 256 threads. 2 grid barriers per step.
// X is ping-ponged by step parity: phase2 reads X[t&1], writes h-cols into
// X[(t+1)&1]  (fixes the round-2 same-phase read/write race).
__device__ __forceinline__ void gridbar(unsigned* cnt) {
    __syncthreads();
    if (threadIdx.x == 0) {
        unsigned arrive = __hip_atomic_fetch_add(cnt, 1u, __ATOMIC_ACQ_REL,
                                                 __HIP_MEMORY_SCOPE_AGENT);
        unsigned target = (arrive / NBLK + 1u) * NBLK;
        long guard = 0;
        while (__hip_atomic_load(cnt, __ATOMIC_RELAXED, __HIP_MEMORY_SCOPE_AGENT) < target) {
            __builtin_amdgcn_s_sleep(2);
            if (++guard > (1L << 31)) break;
        }
        (void)__hip_atomic_load(cnt, __ATOMIC_ACQUIRE, __HIP_MEMORY_SCOPE_AGENT);
    }
    __syncthreads();
}

__global__ __launch_bounds__(256) void k_recur_coop(
        const float* __restrict__ enc, const float* __restrict__ att1T,
        const float* __restrict__ WdaT, const float* __restrict__ W_full,
        const unsigned short* __restrict__ Wgh, const unsigned short* __restrict__ Wgl,
        const float* __restrict__ embW, const float* __restrict__ h0,
        const float* __restrict__ c0, float* __restrict__ hbuf,
        unsigned short* __restrict__ Xb,
        unsigned short* __restrict__ Hbf, float* __restrict__ out_alpha,
        unsigned* __restrict__ cnt) {
    const int g = blockIdx.x, tid = threadIdx.x;
    const int b1 = g >> 2, q1 = g & 3;             // phase-1 assignment
    const int lane = tid & 63, w = tid >> 6;

    __shared__ __align__(16) unsigned short WLh_l[16 * 776];
    __shared__ __align__(16) unsigned short WLl_l[16 * 776];
    __shared__ float wf_l[256], h_l[256], att2_l[256], alpha_l[256], ctxp[256];
    __shared__ float red_l[8];
    __shared__ float gates_l[64 * 20];

    float c = 0.f;

    // ---- prologue ----
    wf_l[tid] = W_full[tid];
    if (g < 64) {
        // stage gate-weight slice (j' rows 16g..16g+16) into LDS
        for (int i = tid; i < 1536; i += 256) {
            int r = i / 96, cp = (i % 96) * 8;
            *reinterpret_cast<uint4*>(&WLh_l[r * 776 + cp]) =
                *reinterpret_cast<const uint4*>(&Wgh[(size_t)(16 * g + r) * XW_ + cp]);
            *reinterpret_cast<uint4*>(&WLl_l[r * 776 + cp]) =
                *reinterpret_cast<const uint4*>(&Wgl[(size_t)(16 * g + r) * XW_ + cp]);
        }
        // copy h0 -> hbuf + X[0] h-part
        int idx = g * 256 + tid;
        float hv = h0[idx];
        hbuf[idx] = hv;
        int bb = idx >> 8, dd = idx & 255;
        unsigned short hi = f2bf(hv);
        Xb[bb * XW_ + ENC_ + dd] = hi;                     // parity 0 hi
        Xb[49152 + bb * XW_ + ENC_ + dd] = f2bf(hv - bf2f(hi));  // parity 0 lo
        // c registers: thread (b = tid>>2, dl = tid&3)
        c = c0[(tid >> 2) * 256 + g * 4 + (tid & 3)];
    }
    gridbar(cnt);

    const float* att1b = att1T + (size_t)b1 * (ATT_ * P_);
    const float* encb  = enc   + (size_t)b1 * P_ * ENC_;

    for (int t = 0; t < T_; t++) {
        unsigned short* Xh_t = Xb + (size_t)(t & 1) * XPAR;        // read buffer (this step)
        unsigned short* Xl_t = Xh_t + 49152;
        unsigned short* Xh_n = Xb + (size_t)((t + 1) & 1) * XPAR;  // write buffer (h for next step)
        unsigned short* Xl_n = Xh_n + 49152;

        // ================= PHASE 1 =================
        h_l[tid] = hbuf[b1 * 256 + tid];
        __syncthreads();
        // att2 (thread = a) -- replicated across the 4 co-b blocks
        {
            float a2 = 0.f;
#pragma unroll 4
            for (int d = 0; d < DEC_; d++) a2 += WdaT[d * ATT_ + tid] * h_l[d];
            att2_l[tid] = a2;
        }
        __syncthreads();
        // scores + softmax (thread = p)
        {
            float s = -1e30f;
            if (tid < P_) {
                s = 0.f;
#pragma unroll 4
                for (int a = 0; a < ATT_; a++) {
                    float v = att1b[(size_t)a * P_ + tid] + att2_l[a];
                    s += fmaxf(v, 0.f) * wf_l[a];
                }
            }
            float m = s;
#pragma unroll
            for (int off = 32; off; off >>= 1) m = fmaxf(m, __shfl_xor(m, off));
            if (lane == 0) red_l[w] = m;
            __syncthreads();
            m = fmaxf(fmaxf(red_l[0], red_l[1]), fmaxf(red_l[2], red_l[3]));
            float ex = (tid < P_) ? __expf(s - m) : 0.f;
            float sm = ex;
#pragma unroll
            for (int off = 32; off; off >>= 1) sm += __shfl_xor(sm, off);
            if (lane == 0) red_l[4 + w] = sm;
            __syncthreads();
            sm = red_l[4] + red_l[5] + red_l[6] + red_l[7];
            float alpha = ex / sm;
            alpha_l[tid] = alpha;
            if (q1 == 0 && tid < P_)
                out_alpha[(size_t)b1 * (T_ * P_) + t * P_ + tid] = alpha;
        }
        __syncthreads();
        // ctx e-quarter: thread (e_local = tid&127, ph = tid>>7); writes X[t&1] ctx cols
        {
            int el = tid & 127, ph = tid >> 7;
            int e = q1 * 128 + el;
            float cx = 0.f;
            const float* ep = encb + (size_t)(98 * ph) * ENC_ + e;
#pragma unroll 2
            for (int p = 0; p < 98; p++)
                cx += alpha_l[98 * ph + p] * ep[(size_t)p * ENC_];
            ctxp[tid] = cx;
            __syncthreads();
            if (tid < 128) {
                float v = ctxp[tid] + ctxp[tid + 128];
                int eg = q1 * 128 + tid;
                unsigned short hi = f2bf(v);
                Xh_t[b1 * XW_ + eg] = hi;
                Xl_t[b1 * XW_ + eg] = f2bf(v - bf2f(hi));
            }
        }
        gridbar(cnt);

        // ================= PHASE 2 (blocks 0..63) =================
        if (g < 64) {
            // wave w: m-tile rows 16w..16w+16 (m=b), n = 16 j' (this block's slice)
            const unsigned short* xhp = Xh_t + (size_t)(16 * w + (lane & 15)) * XW_ + ((lane >> 4) * 8);
            const unsigned short* xlp = Xl_t + (size_t)(16 * w + (lane & 15)) * XW_ + ((lane >> 4) * 8);
            const unsigned short* blhp = &WLh_l[(lane & 15) * 776 + (lane >> 4) * 8];
            const unsigned short* bllp = &WLl_l[(lane & 15) * 776 + (lane >> 4) * 8];
            f32x4 acc = {0.f, 0.f, 0.f, 0.f};
#pragma unroll 4
            for (int k0 = 0; k0 < XW_; k0 += 32) {
                short8 ah = *reinterpret_cast<const short8*>(xhp + k0);
                short8 al = *reinterpret_cast<const short8*>(xlp + k0);
                short8 bh = *reinterpret_cast<const short8*>(blhp + k0);
                short8 bl = *reinterpret_cast<const short8*>(bllp + k0);
                acc = __builtin_amdgcn_mfma_f32_16x16x32_bf16(ah, bh, acc, 0, 0, 0);
                acc = __builtin_amdgcn_mfma_f32_16x16x32_bf16(al, bh, acc, 0, 0, 0);
                acc = __builtin_amdgcn_mfma_f32_16x16x32_bf16(ah, bl, acc, 0, 0, 0);
            }
            // dump to LDS: C row m = 16w + (lane>>4)*4 + r, col n = lane&15
            {
                int n = lane & 15, rb = 16 * w + (lane >> 4) * 4;
#pragma unroll
                for (int r = 0; r < 4; r++) gates_l[(rb + r) * 20 + n] = acc[r];
            }
            __syncthreads();
            // pointwise: thread (b = tid>>2, dl = tid&3)
            {
                int b = tid >> 2, dl = tid & 3;
                float4 gg = *reinterpret_cast<const float4*>(&gates_l[b * 20 + dl * 4]);
                float4 ee = *reinterpret_cast<const float4*>(
                    &embW[((size_t)t * B_ + b) * G4_ + g * 16 + dl * 4]);
                float i_g = 1.f / (1.f + __expf(-(gg.x + ee.x)));
                float f_g = 1.f / (1.f + __expf(-(gg.y + ee.y)));
                float g_g = tanhf(gg.z + ee.z);
                float o_g = 1.f / (1.f + __expf(-(gg.w + ee.w)));
                c = f_g * c + i_g * g_g;
                float hn = o_g * tanhf(c);
                int d = g * 4 + dl;
                hbuf[b * 256 + d] = hn;
                unsigned short hi = f2bf(hn);
                Xh_n[b * XW_ + ENC_ + d] = hi;             // write NEXT parity buffer
                Xl_n[b * XW_ + ENC_ + d] = f2bf(hn - bf2f(hi));
                Hbf[((size_t)t * B_ + b) * DEC_ + d] = f2bf(hn);
            }
        }
        gridbar(cnt);
    }
}

// ---------- logits: bf16 MFMA ----------
__global__ __launch_bounds__(256) void k_logits(
        const unsigned short* __restrict__ Hbf, const unsigned short* __restrict__ Woutbf,
        const float* __restrict__ b_out, float* __restrict__ out) {
    int n0 = blockIdx.x * 128, m0 = blockIdx.y * 128;
    __shared__ __align__(16) unsigned short At[128][40];
    __shared__ __align__(16) unsigned short Bt[128][40];
    int tid = threadIdx.x;
    int lane = tid & 63, w = tid >> 6;
    int wm = (w & 1) * 64, wn = (w >> 1) * 64;
    f32x4 acc[4][4];
#pragma unroll
    for (int i = 0; i < 4; i++)
#pragma unroll
        for (int j = 0; j < 4; j++) acc[i][j] = (f32x4){0.f, 0.f, 0.f, 0.f};

    for (int k0 = 0; k0 < DEC_; k0 += 32) {
#pragma unroll
        for (int l = 0; l < 2; l++) {
            int idx = l * 256 + tid;
            int r = idx >> 2, kc = (idx & 3) * 8;
            uint4 av = *reinterpret_cast<const uint4*>(&Hbf[(size_t)(m0 + r) * DEC_ + k0 + kc]);
            *reinterpret_cast<uint4*>(&At[r][kc]) = av;
            uint4 bv = make_uint4(0u, 0u, 0u, 0u);
            if (n0 + r < V_)
                bv = *reinterpret_cast<const uint4*>(&Woutbf[(size_t)(n0 + r) * DEC_ + k0 + kc]);
            *reinterpret_cast<uint4*>(&Bt[r][kc]) = bv;
        }
        __syncthreads();
        int qk = (lane >> 4) * 8, fr = lane & 15;
        short8 a[4], bb[4];
#pragma unroll
        for (int i = 0; i < 4; i++) {
            a[i]  = *reinterpret_cast<const short8*>(&At[wm + i * 16 + fr][qk]);
            bb[i] = *reinterpret_cast<const short8*>(&Bt[wn + i * 16 + fr][qk]);
        }
#pragma unroll
        for (int i = 0; i < 4; i++)
#pragma unroll
            for (int j = 0; j < 4; j++)
                acc[i][j] = __builtin_amdgcn_mfma_f32_16x16x32_bf16(a[i], bb[j], acc[i][j], 0, 0, 0);
        __syncthreads();
    }
    int col = lane & 15, qr = (lane >> 4) * 4;
#pragma unroll
    for (int j = 0; j < 4; j++) {
        int n = n0 + wn + j * 16 + col;
        if (n < V_) {
            float bo = b_out[n];
#pragma unroll
            for (int i = 0; i < 4; i++)
#pragma unroll
                for (int r = 0; r < 4; r++) {
                    int m = m0 + wm + i * 16 + qr + r;
                    int t = m >> 6, b = m & 63;
                    out[(size_t)b * (T_ * V_) + (size_t)t * V_ + n] = acc[i][j][r] + bo;
                }
        }
    }
}

// ---------- launch ----------
extern "C" void kernel_launch(void* const* d_in, const int* in_sizes, int n_in,
                              void* d_out, int out_size, void* d_ws, size_t ws_size,
                              hipStream_t stream) {
    const float* enc       = (const float*)d_in[0];
    const int*   caption   = (const int*)d_in[1];
    const float* W_enc_att = (const float*)d_in[2];
    const float* W_dec_att = (const float*)d_in[3];
    const float* W_full    = (const float*)d_in[4];
    const float* embedding = (const float*)d_in[5];
    const float* W_init_h  = (const float*)d_in[6];
    const float* b_init_h  = (const float*)d_in[7];
    const float* W_init_c  = (const float*)d_in[8];
    const float* b_init_c  = (const float*)d_in[9];
    const float* W_ih      = (const float*)d_in[10];
    const float* b_ih      = (const float*)d_in[11];
    const float* W_hh      = (const float*)d_in[12];
    const float* b_hh      = (const float*)d_in[13];
    const float* W_out     = (const float*)d_in[14];
    const float* b_out     = (const float*)d_in[15];

    float* ws = (float*)d_ws;
    unsigned* cnt   = (unsigned*)ws;                      // 16 floats reserved
    float* h0       = ws + 16;          // 16384
    float* c0       = ws + 16400;       // 16384
    float* WdaT     = ws + 32784;       // 65536  [d][a] fp32
    float* att1T    = ws + 98320;       // 3211264 [b][a][p] fp32
    float* embW     = ws + 3309584;     // 2883584 [t*64+b][j'] fp32 (biases included)
    float* hbuf     = ws + 6193168;     // 16384
    unsigned short* Wgh = (unsigned short*)(ws + 6209552);   // 1024x768 shorts
    unsigned short* Wgl = (unsigned short*)(ws + 6602768);   // 1024x768 shorts
    unsigned short* Xb  = (unsigned short*)(ws + 6995984);   // 2 parities x (Xh+Xl) = 196608 shorts
    unsigned short* Hbf = (unsigned short*)(ws + 7094288);   // 2816x256 shorts
    unsigned short* Woutbf = (unsigned short*)(ws + 7454736);// 10000x256 shorts
    // WiheT aliases Hbf region (only live until k_embW completes, before k_recur)
    float* WiheT    = ws + 7094288;     // 262144 floats

    float* out_pred  = (float*)d_out;
    float* out_alpha = out_pred + (size_t)B_ * T_ * V_;

    hipMemsetAsync(cnt, 0, 64, stream);
    k_transpose<<<dim3(8, 8),  256, 0, stream>>>(W_dec_att, WdaT, ATT_, DEC_, 0);
    k_transpose<<<dim3(8, 32), 256, 0, stream>>>(W_ih, WiheT, G4_, XW_, ENC_);
    k_prepW<<<1024, 256, 0, stream>>>(W_ih, W_hh, Wgh, Wgl);
    k_cvt<<<10000, 256, 0, stream>>>(W_out, Woutbf, V_ * DEC_);
    k_init_state<<<B_, 256, 0, stream>>>(enc, W_init_h, b_init_h, W_init_c, b_init_c, h0, c0);
    k_att1<<<B_ * 4, 256, 0, stream>>>(enc, W_enc_att, att1T);
    k_embW<<<176, 256, 0, stream>>>(caption, embedding, WiheT, b_ih, b_hh, embW);
    k_recur_coop<<<NBLK, 256, 0, stream>>>(enc, att1T, WdaT, W_full, Wgh, Wgl, embW,
                                           h0, c0, hbuf, Xb, Hbf, out_alpha, cnt);
    k_logits<<<dim3(79, 22), 256, 0, stream>>>(Hbf, Woutbf, b_out, out_pred);
}